// Round 16
// baseline (325.649 us; speedup 1.0000x reference)
//
#include <hip/hip_runtime.h>
#include <hip/hip_bf16.h>

typedef int int32x4 __attribute__((ext_vector_type(4)));
typedef signed char i8;

#define B_ 2
#define S_ 1024
#define E_ 4096
#define H_ 16
#define D_ 256

#define MFMA_I8(a, b, c) __builtin_amdgcn_mfma_i32_16x16x64_i8((a), (b), (c), 0, 0, 0)

__device__ __forceinline__ int32x4 ld16(const void* p) {
    return *reinterpret_cast<const int32x4*>(p);
}

// async global->LDS, 16B per lane. LDS dest = wave-uniform base + lane*16.
__device__ __forceinline__ void gload16(const void* g, void* l) {
    __builtin_amdgcn_global_load_lds(
        (const __attribute__((address_space(1))) void*)g,
        (__attribute__((address_space(3))) void*)l, 16, 0, 0);
}

#define WAIT_VM3()  asm volatile("s_waitcnt vmcnt(3)" ::: "memory")
#define WAIT_VM0()  asm volatile("s_waitcnt vmcnt(0)" ::: "memory")
#define COMPILER_FENCE() asm volatile("" ::: "memory")

// ---------------- fp32 (integer-valued) -> int8, coalesced ----------------
__device__ __forceinline__ int pack4(float4 f) {
    union { int w; i8 b[4]; } u;
    u.b[0] = (i8)f.x; u.b[1] = (i8)f.y; u.b[2] = (i8)f.z; u.b[3] = (i8)f.w;
    return u.w;
}

__global__ void k_f32_to_i8(const float* __restrict__ src, i8* __restrict__ dst, int n4) {
    int i = blockIdx.x * blockDim.x + threadIdx.x;
    if (i >= n4) return;
    reinterpret_cast<int*>(dst)[i] = pack4(reinterpret_cast<const float4*>(src)[i]);
}

// 4 weight matrices in one launch (blockIdx.y selects matrix)
__global__ void k_w_to_i8(const float* __restrict__ w0, const float* __restrict__ w1,
                          const float* __restrict__ w2, const float* __restrict__ w3,
                          i8* __restrict__ d0, i8* __restrict__ d1,
                          i8* __restrict__ d2, i8* __restrict__ d3, int n4) {
    int i = blockIdx.x * blockDim.x + threadIdx.x;
    if (i >= n4) return;
    const float* src = (blockIdx.y == 0) ? w0 : (blockIdx.y == 1) ? w1 : (blockIdx.y == 2) ? w2 : w3;
    i8* dst = (blockIdx.y == 0) ? d0 : (blockIdx.y == 1) ? d1 : (blockIdx.y == 2) ? d2 : d3;
    reinterpret_cast<int*>(dst)[i] = pack4(reinterpret_cast<const float4*>(src)[i]);
}

// ---------------- sin/cos table [S][32] ----------------
__global__ void k_sincos(float* __restrict__ sin_t, float* __restrict__ cos_t) {
    int idx = blockIdx.x * blockDim.x + threadIdx.x;
    if (idx >= S_ * 32) return;
    int s = idx >> 5, i = idx & 31;
    float ex = (float)(2 * i) / 64.0f;
    float invf = 1.0f / powf(10000.0f, ex);
    float arg = (float)s * invf;
    sin_t[idx] = (float)sin((double)arg);
    cos_t[idx] = (float)cos((double)arg);
}

// ============== R8 GEMM core (known-good) ==============
// BM=256, BN=128, BK=64, 8 waves (4M x 2N), per-wave 64x64, triple-buffered
// 72KB LDS, counted vmcnt(3), XOR granule swizzle (0 conflicts verified).
template<bool OUT_I8>
__device__ __forceinline__ void gemm_core(
    const i8* __restrict__ X, const i8* __restrict__ W, const float* __restrict__ bias,
    void* __restrict__ out, float alpha, int M, int N, int K, i8* lds)
{
    const int nt = K >> 6;
    const int nwg = (M >> 8) * (N >> 7);
    const int q = nwg >> 3;
    const int lin = blockIdx.x;
    const int wg = (lin & 7) * q + (lin >> 3);
    const int nbm = M >> 8;
    const int m0 = (wg % nbm) * 256, n0 = (wg / nbm) * 128;

    const int tid = threadIdx.x, lane = tid & 63, wave = tid >> 6;
    const int wr = wave >> 1, wc = wave & 1, l4 = lane & 15, lh = lane >> 4;

    const int g4 = lh ^ ((l4 >> 1) & 3);
    const int aoff = (wr * 64 + l4) * 64 + g4 * 16;
    const int boff = 16384 + (wc * 64 + l4) * 64 + g4 * 16;

    const int srow = tid >> 2;
    const int sg = (tid & 3) ^ ((tid >> 3) & 3);
    const i8* Asrc = X + (size_t)(m0 + srow) * K + sg * 16;
    const i8* Bsrc = W + (size_t)(n0 + srow) * K + sg * 16;
    const size_t rstep = (size_t)128 * K;
    const int ldst = wave * 1024;

#define BUF3(t_) (lds + ((t_) % 3) * 24576)
#define STAGE3(t_) do { int kb_ = (t_) * 64; i8* lb_ = BUF3(t_);             \
        gload16(Asrc + kb_,         lb_ + ldst);                             \
        gload16(Asrc + rstep + kb_, lb_ + 8192 + ldst);                      \
        gload16(Bsrc + kb_,         lb_ + 16384 + ldst); } while (0)

    int32x4 acc[4][4];
#pragma unroll
    for (int m = 0; m < 4; ++m)
#pragma unroll
        for (int n = 0; n < 4; ++n) acc[m][n] = int32x4{0, 0, 0, 0};

    STAGE3(0);
    STAGE3(1);

    for (int t = 0; t < nt; ++t) {
        const i8* Tb = BUF3(t);
        if (t + 1 < nt) { WAIT_VM3(); } else { WAIT_VM0(); }
        __builtin_amdgcn_s_barrier();
        COMPILER_FENCE();

        if (t + 2 < nt) STAGE3(t + 2);

        int32x4 a0, a1, a2, a3, b0, b1, b2, b3;
        a0 = ld16(Tb + aoff);
        b0 = ld16(Tb + boff);        b1 = ld16(Tb + boff + 1024);
        b2 = ld16(Tb + boff + 2048); b3 = ld16(Tb + boff + 3072);
        a1 = ld16(Tb + aoff + 1024);
        a2 = ld16(Tb + aoff + 2048); a3 = ld16(Tb + aoff + 3072);
        __builtin_amdgcn_s_setprio(1);
        acc[0][0] = MFMA_I8(a0, b0, acc[0][0]);
        acc[0][1] = MFMA_I8(a0, b1, acc[0][1]);
        acc[0][2] = MFMA_I8(a0, b2, acc[0][2]);
        acc[0][3] = MFMA_I8(a0, b3, acc[0][3]);
        acc[1][0] = MFMA_I8(a1, b0, acc[1][0]);
        acc[1][1] = MFMA_I8(a1, b1, acc[1][1]);
        acc[1][2] = MFMA_I8(a1, b2, acc[1][2]);
        acc[1][3] = MFMA_I8(a1, b3, acc[1][3]);
        acc[2][0] = MFMA_I8(a2, b0, acc[2][0]);
        acc[2][1] = MFMA_I8(a2, b1, acc[2][1]);
        acc[2][2] = MFMA_I8(a2, b2, acc[2][2]);
        acc[2][3] = MFMA_I8(a2, b3, acc[2][3]);
        acc[3][0] = MFMA_I8(a3, b0, acc[3][0]);
        acc[3][1] = MFMA_I8(a3, b1, acc[3][1]);
        acc[3][2] = MFMA_I8(a3, b2, acc[3][2]);
        acc[3][3] = MFMA_I8(a3, b3, acc[3][3]);
        __builtin_amdgcn_s_setprio(0);
    }
#undef BUF3
#undef STAGE3

#pragma unroll
    for (int m = 0; m < 4; ++m)
#pragma unroll
        for (int n = 0; n < 4; ++n)
#pragma unroll
            for (int r = 0; r < 4; ++r) {
                int grow = m0 + wr * 64 + m * 16 + lh * 4 + r;
                int gcol = n0 + wc * 64 + n * 16 + l4;
                float y = alpha * (float)acc[m][n][r] + bias[gcol];
                if (OUT_I8) {
                    float v = rintf(y);
                    v = fminf(fmaxf(v, -128.0f), 127.0f);
                    reinterpret_cast<i8*>(out)[(size_t)grow * N + gcol] = (i8)v;
                } else {
                    reinterpret_cast<float*>(out)[(size_t)grow * N + gcol] = y;
                }
            }
}

// fused Q/K/V projection: blockIdx.z selects weight/bias/dst
__global__ __launch_bounds__(512, 4) void k_gemm_qkv(
    const i8* __restrict__ X,
    const i8* __restrict__ w0, const i8* __restrict__ w1, const i8* __restrict__ w2,
    const float* __restrict__ b0, const float* __restrict__ b1, const float* __restrict__ b2,
    i8* __restrict__ o0, i8* __restrict__ o1, i8* __restrict__ o2,
    float alpha, int M, int N, int K)
{
    __shared__ __align__(16) i8 lds[3 * 24576];
    int z = blockIdx.z;
    const i8* W = (z == 0) ? w0 : (z == 1) ? w1 : w2;
    const float* bias = (z == 0) ? b0 : (z == 1) ? b1 : b2;
    i8* out = (z == 0) ? o0 : (z == 1) ? o1 : o2;
    gemm_core<true>(X, W, bias, out, alpha, M, N, K, lds);
}

__global__ __launch_bounds__(512, 4) void k_gemm_out(
    const i8* __restrict__ X, const i8* __restrict__ W, const float* __restrict__ bias,
    float* __restrict__ out, float alpha, int M, int N, int K)
{
    __shared__ __align__(16) i8 lds[3 * 24576];
    gemm_core<false>(X, W, bias, out, alpha, M, N, K, lds);
}

// ---------------- rope, vectorized: (B,S,H,D) -> (B,H,S,D) ----------------
__global__ void k_rope(const i8* __restrict__ qin, const i8* __restrict__ kin,
                       i8* __restrict__ qout, i8* __restrict__ kout,
                       const float* __restrict__ sin_t, const float* __restrict__ cos_t)
{
    const i8* in = blockIdx.y ? kin : qin;
    i8* outp = blockIdx.y ? kout : qout;
    int t = threadIdx.x;
    int row = blockIdx.x * 16 + (t >> 4);   // (b*S + s)*H + h
    int seg = t & 15;
    int b = row >> 14;                      // / (S*H)
    int s = (row >> 4) & 1023;
    int h = row & 15;
    union { int32x4 v; i8 b8[16]; } u;
    u.v = ld16(in + (size_t)row * D_ + seg * 16);
    if (seg < 4) {                          // d = seg*16 + j < 64
#pragma unroll
        for (int j = 0; j < 16; j += 2) {
            int i = (seg * 16 + j) >> 1;
            float c = cos_t[s * 32 + i], sn = sin_t[s * 32 + i];
            float f1 = (float)u.b8[j], f2 = (float)u.b8[j + 1];
            float r0 = __fadd_rn(__fmul_rn(f1, c), __fmul_rn(-f2, sn));
            float r1 = __fadd_rn(__fmul_rn(f2, c), __fmul_rn(f1, sn));
            u.b8[j]     = (i8)truncf(fminf(fmaxf(r0, -128.0f), 127.0f));
            u.b8[j + 1] = (i8)truncf(fminf(fmaxf(r1, -128.0f), 127.0f));
        }
    }
    *reinterpret_cast<int32x4*>(
        outp + ((size_t)(b * H_ + h) * S_ + s) * D_ + seg * 16) = u.v;
}

// ---------------- V transpose: (B,S,H,D) -> (B,H,D,S) ----------------
__global__ void k_vtrans(const i8* __restrict__ vin, i8* __restrict__ vout) {
    __shared__ int tile[64][17];
    int bh = blockIdx.z;
    int b = bh >> 4, h = bh & 15;
    int s0 = blockIdx.x * 64, d0 = blockIdx.y * 64;
    int t = threadIdx.x;
    {
        int sr = t >> 2, dq = (t & 3) * 16;
        int32x4 v = ld16(vin + ((size_t)(b * S_ + s0 + sr) * H_ + h) * D_ + d0 + dq);
#pragma unroll
        for (int j = 0; j < 4; ++j) tile[sr][dq / 4 + j] = v[j];
    }
    __syncthreads();
    {
        int dr = t >> 2, sq = (t & 3) * 16;
        union { int32x4 v; i8 b[16]; } u;
        const i8* tb = reinterpret_cast<const i8*>(tile);
#pragma unroll
        for (int j = 0; j < 16; ++j) u.b[j] = tb[(sq + j) * 68 + dr];
        *reinterpret_cast<int32x4*>(vout + ((size_t)bh * D_ + d0 + dr) * S_ + s0 + sq) = u.v;
    }
}

// ---------------- fused int8 attention ----------------
// Q,K: (B,H,S,D) post-rope. V: (B,H,D,S). O: (B,S,H,D).
// No-max softmax. K-fragment REGISTER PREFETCH (double-buffer, 1 tile ahead)
// in both phases hides L2 latency under MFMA+softmax.
struct AttnShared {
    float slx[4][32];
    float r127[32];
    __align__(16) i8 plds[32][80];
};

#define LOADK(dst_, kt_) do {                                                 \
        const i8* kp_ = Kb + (size_t)((kt_) * 64 + wave * 16 + l4) * D_ + lh * 16; \
        dst_[0] = ld16(kp_);       dst_[1] = ld16(kp_ + 64);                  \
        dst_[2] = ld16(kp_ + 128); dst_[3] = ld16(kp_ + 192); } while (0)

__device__ __forceinline__ void attn_chunk(int qc, int bh, int tid,
    const i8* __restrict__ Qh, const i8* __restrict__ Kb, const i8* __restrict__ Vb,
    i8* __restrict__ O, AttnShared& sh)
{
    const float C2 = 1.25e-5f * 1.44269504088896f;   // A_QK/16 * log2(e)
    const float APV = 1.0f / 127.0f;
    const int lane = tid & 63, wave = tid >> 6;
    const int l4 = lane & 15, lh = lane >> 4;
    const i8* Qb = Qh + (size_t)(qc * 32) * D_;
    const int nt = (qc * 32 + 31) / 64 + 1;

    int32x4 aq[2][4];
#pragma unroll
    for (int m = 0; m < 2; ++m)
#pragma unroll
        for (int kk = 0; kk < 4; ++kk)
            aq[m][kk] = ld16(Qb + (size_t)(m * 16 + l4) * D_ + kk * 64 + lh * 16);

    float sum_[2][4];
#pragma unroll
    for (int m = 0; m < 2; ++m)
#pragma unroll
        for (int r = 0; r < 4; ++r) sum_[m][r] = 0.0f;

    int32x4 kA[4], kB[4];

    // ---- Phase A: lane-local exp-sums, K double-buffered
#define BODY_A(kt_, kf_) do {                                                 \
        int32x4 acc0 = int32x4{0,0,0,0}, acc1 = int32x4{0,0,0,0};             \
        acc0 = MFMA_I8(aq[0][0], kf_[0], acc0);                               \
        acc1 = MFMA_I8(aq[1][0], kf_[0], acc1);                               \
        acc0 = MFMA_I8(aq[0][1], kf_[1], acc0);                               \
        acc1 = MFMA_I8(aq[1][1], kf_[1], acc1);                               \
        acc0 = MFMA_I8(aq[0][2], kf_[2], acc0);                               \
        acc1 = MFMA_I8(aq[1][2], kf_[2], acc1);                               \
        acc0 = MFMA_I8(aq[0][3], kf_[3], acc0);                               \
        acc1 = MFMA_I8(aq[1][3], kf_[3], acc1);                               \
        int gcol = (kt_) * 64 + wave * 16 + l4;                               \
        _Pragma("unroll")                                                     \
        for (int m = 0; m < 2; ++m) {                                         \
            int32x4 accm = m ? acc1 : acc0;                                   \
            _Pragma("unroll")                                                 \
            for (int r = 0; r < 4; ++r) {                                     \
                int grow = qc * 32 + m * 16 + lh * 4 + r;                     \
                float e = (gcol <= grow) ? exp2f((float)accm[r] * C2) : 0.0f; \
                sum_[m][r] += e;                                              \
            }                                                                 \
        }                                                                     \
    } while (0)

    LOADK(kA, 0);
    for (int kt = 0; kt < nt; kt += 2) {
        if (kt + 1 < nt) LOADK(kB, kt + 1);
        BODY_A(kt, kA);
        if (kt + 1 < nt) {
            if (kt + 2 < nt) LOADK(kA, kt + 2);
            BODY_A(kt + 1, kB);
        }
    }
#undef BODY_A

#pragma unroll
    for (int m = 0; m < 2; ++m)
#pragma unroll
        for (int r = 0; r < 4; ++r) {
            float s = sum_[m][r];
            s += __shfl_xor(s, 1);
            s += __shfl_xor(s, 2);
            s += __shfl_xor(s, 4);
            s += __shfl_xor(s, 8);
            if (l4 == 0) sh.slx[wave][m * 16 + lh * 4 + r] = s;
        }
    __syncthreads();
    if (tid < 32)
        sh.r127[tid] = 127.0f /
            (sh.slx[0][tid] + sh.slx[1][tid] + sh.slx[2][tid] + sh.slx[3][tid]);
    __syncthreads();

    int32x4 oacc[2][4];
#pragma unroll
    for (int m = 0; m < 2; ++m)
#pragma unroll
        for (int n = 0; n < 4; ++n) oacc[m][n] = int32x4{0, 0, 0, 0};

    // ---- Phase B: recompute scores, quantize p, PV; K double-buffered
#define BODY_B(kt_, kf_) do {                                                 \
        int32x4 acc0 = int32x4{0,0,0,0}, acc1 = int32x4{0,0,0,0};             \
        acc0 = MFMA_I8(aq[0][0], kf_[0], acc0);                               \
        acc1 = MFMA_I8(aq[1][0], kf_[0], acc1);                               \
        acc0 = MFMA_I8(aq[0][1], kf_[1], acc0);                               \
        acc1 = MFMA_I8(aq[1][1], kf_[1], acc1);                               \
        acc0 = MFMA_I8(aq[0][2], kf_[2], acc0);                               \
        acc1 = MFMA_I8(aq[1][2], kf_[2], acc1);                               \
        acc0 = MFMA_I8(aq[0][3], kf_[3], acc0);                               \
        acc1 = MFMA_I8(aq[1][3], kf_[3], acc1);                               \
        int gcol = (kt_) * 64 + wave * 16 + l4;                               \
        i8 pv[2][4];                                                          \
        _Pragma("unroll")                                                     \
        for (int m = 0; m < 2; ++m) {                                         \
            int32x4 accm = m ? acc1 : acc0;                                   \
            _Pragma("unroll")                                                 \
            for (int r = 0; r < 4; ++r) {                                     \
                int rowi = m * 16 + lh * 4 + r;                               \
                int grow = qc * 32 + rowi;                                    \
                float e = (gcol <= grow) ? exp2f((float)accm[r] * C2) : 0.0f; \
                pv[m][r] = (i8)(int)rintf(e * sh.r127[rowi]);                 \
            }                                                                 \
        }                                                                     \
        __syncthreads();                                                      \
        _Pragma("unroll")                                                     \
        for (int m = 0; m < 2; ++m)                                           \
            _Pragma("unroll")                                                 \
            for (int r = 0; r < 4; ++r)                                       \
                sh.plds[m * 16 + lh * 4 + r][wave * 16 + l4] = pv[m][r];      \
        __syncthreads();                                                      \
        int32x4 a0 = ld16(&sh.plds[l4][lh * 16]);                             \
        int32x4 a1 = ld16(&sh.plds[16 + l4][lh * 16]);                        \
        const i8* vp_ = Vb + (size_t)(wave * 64 + l4) * S_ + (kt_) * 64 + lh * 16; \
        _Pragma("unroll")                                                     \
        for (int n = 0; n < 4; ++n) {                                         \
            int32x4 bf = ld16(vp_ + (size_t)(n * 16) * S_);                   \
            oacc[0][n] = MFMA_I8(a0, bf, oacc[0][n]);                         \
            oacc[1][n] = MFMA_I8(a1, bf, oacc[1][n]);                         \
        }                                                                     \
    } while (0)

    LOADK(kA, 0);
    for (int kt = 0; kt < nt; kt += 2) {
        if (kt + 1 < nt) LOADK(kB, kt + 1);
        BODY_B(kt, kA);
        if (kt + 1 < nt) {
            if (kt + 2 < nt) LOADK(kA, kt + 2);
            BODY_B(kt + 1, kB);
        }
    }
#undef BODY_B

    int b = bh >> 4, h = bh & 15;
#pragma unroll
    for (int m = 0; m < 2; ++m)
#pragma unroll
        for (int r = 0; r < 4; ++r) {
            int s = qc * 32 + m * 16 + lh * 4 + r;
#pragma unroll
            for (int n = 0; n < 4; ++n) {
                float o = rintf(APV * (float)oacc[m][n][r]);
                o = fminf(fmaxf(o, -128.0f), 127.0f);
                O[((size_t)(b * S_ + s) * H_ + h) * D_ + wave * 64 + n * 16 + l4] = (i8)o;
            }
        }
}

// One chunk per block: 1024 blocks = 4 blocks/CU (2x the paired TLP).
// Longest chunks dispatch first (qc = 31 - blockIdx.x) for back-fill.
__global__ __launch_bounds__(256) void k_attn(const i8* __restrict__ Q, const i8* __restrict__ K,
                                              const i8* __restrict__ V, i8* __restrict__ O)
{
    __shared__ AttnShared sh;
    int bh = blockIdx.y;
    int qc = (S_ / 32 - 1) - blockIdx.x;
    int tid = threadIdx.x;
    const i8* Qh = Q + (size_t)bh * S_ * D_;
    const i8* Kb = K + (size_t)bh * S_ * D_;
    const i8* Vb = V + (size_t)bh * D_ * S_;
    attn_chunk(qc, bh, tid, Qh, Kb, Vb, O, sh);
}

extern "C" void kernel_launch(void* const* d_in, const int* in_sizes, int n_in,
                              void* d_out, int out_size, void* d_ws, size_t ws_size,
                              hipStream_t stream) {
    const float* hs = (const float*)d_in[0];
    const float* Wq = (const float*)d_in[1];
    const float* Wk = (const float*)d_in[2];
    const float* Wv = (const float*)d_in[3];
    const float* Wo = (const float*)d_in[4];
    const float* bq = (const float*)d_in[5];
    const float* bk = (const float*)d_in[6];
    const float* bv = (const float*)d_in[7];
    const float* bo = (const float*)d_in[8];
    float* out = (float*)d_out;

    size_t off = 0;
    char* wsb = (char*)d_ws;
    auto carve = [&](size_t bytes) { char* p = wsb + off; off += (bytes + 255) & ~(size_t)255; return p; };
    const size_t ME = (size_t)B_ * S_ * E_;   // 8.4 MB
    const size_t EE = (size_t)E_ * E_;        // 16.8 MB
    i8* x8  = (i8*)carve(ME);
    i8* wq8 = (i8*)carve(EE);
    i8* wk8 = (i8*)carve(EE);
    i8* wv8 = (i8*)carve(EE);
    i8* wo8 = (i8*)carve(EE);
    i8* q8  = (i8*)carve(ME);
    i8* k8  = (i8*)carve(ME);
    i8* v8  = (i8*)carve(ME);
    i8* qr  = (i8*)carve(ME);
    i8* kr  = (i8*)carve(ME);
    i8* vt  = (i8*)carve(ME);
    i8* o8  = (i8*)carve(ME);
    float* sin_t = (float*)carve((size_t)S_ * 32 * 4);
    float* cos_t = (float*)carve((size_t)S_ * 32 * 4);

    int n4_me = (int)(ME / 4), n4_ee = (int)(EE / 4);
    k_f32_to_i8<<<(n4_me + 255) / 256, 256, 0, stream>>>(hs, x8, n4_me);
    k_w_to_i8<<<dim3((n4_ee + 255) / 256, 4), 256, 0, stream>>>(
        Wq, Wk, Wv, Wo, wq8, wk8, wv8, wo8, n4_ee);
    k_sincos<<<(S_ * 32 + 255) / 256, 256, 0, stream>>>(sin_t, cos_t);

    const int M = B_ * S_, N = E_, Kd = E_;
    const int nwg = (M / 256) * (N / 128);   // 256 blocks per z
    k_gemm_qkv<<<dim3(nwg, 1, 3), 512, 0, stream>>>(
        x8, wq8, wk8, wv8, bq, bk, bv, q8, k8, v8, 0.00012f, M, N, Kd);

    k_rope<<<dim3((B_ * S_ * H_) / 16, 2), 256, 0, stream>>>(q8, k8, qr, kr, sin_t, cos_t);
    k_vtrans<<<dim3(S_ / 64, D_ / 64, B_ * H_), 256, 0, stream>>>(v8, vt);
    k_attn<<<dim3(S_ / 32, B_ * H_), 256, 0, stream>>>(qr, kr, vt, o8);

    k_gemm_out<<<nwg, 512, 0, stream>>>(o8, wo8, bo, out, 0.01f, M, N, Kd);
}

// Round 17
// 292.412 us; speedup vs baseline: 1.1137x; 1.1137x over previous
//
#include <hip/hip_runtime.h>
#include <hip/hip_bf16.h>

typedef int int32x4 __attribute__((ext_vector_type(4)));
typedef signed char i8;

#define B_ 2
#define S_ 1024
#define E_ 4096
#define H_ 16
#define D_ 256

#define MFMA_I8(a, b, c) __builtin_amdgcn_mfma_i32_16x16x64_i8((a), (b), (c), 0, 0, 0)

__device__ __forceinline__ int32x4 ld16(const void* p) {
    return *reinterpret_cast<const int32x4*>(p);
}

// async global->LDS, 16B per lane. LDS dest = wave-uniform base + lane*16.
__device__ __forceinline__ void gload16(const void* g, void* l) {
    __builtin_amdgcn_global_load_lds(
        (const __attribute__((address_space(1))) void*)g,
        (__attribute__((address_space(3))) void*)l, 16, 0, 0);
}

#define WAIT_VM3()  asm volatile("s_waitcnt vmcnt(3)" ::: "memory")
#define WAIT_VM0()  asm volatile("s_waitcnt vmcnt(0)" ::: "memory")
#define COMPILER_FENCE() asm volatile("" ::: "memory")

// ---------------- fp32 (integer-valued) -> int8, coalesced ----------------
__device__ __forceinline__ int pack4(float4 f) {
    union { int w; i8 b[4]; } u;
    u.b[0] = (i8)f.x; u.b[1] = (i8)f.y; u.b[2] = (i8)f.z; u.b[3] = (i8)f.w;
    return u.w;
}

__global__ void k_f32_to_i8(const float* __restrict__ src, i8* __restrict__ dst, int n4) {
    int i = blockIdx.x * blockDim.x + threadIdx.x;
    if (i >= n4) return;
    reinterpret_cast<int*>(dst)[i] = pack4(reinterpret_cast<const float4*>(src)[i]);
}

// 4 weight matrices in one launch (blockIdx.y selects matrix)
__global__ void k_w_to_i8(const float* __restrict__ w0, const float* __restrict__ w1,
                          const float* __restrict__ w2, const float* __restrict__ w3,
                          i8* __restrict__ d0, i8* __restrict__ d1,
                          i8* __restrict__ d2, i8* __restrict__ d3, int n4) {
    int i = blockIdx.x * blockDim.x + threadIdx.x;
    if (i >= n4) return;
    const float* src = (blockIdx.y == 0) ? w0 : (blockIdx.y == 1) ? w1 : (blockIdx.y == 2) ? w2 : w3;
    i8* dst = (blockIdx.y == 0) ? d0 : (blockIdx.y == 1) ? d1 : (blockIdx.y == 2) ? d2 : d3;
    reinterpret_cast<int*>(dst)[i] = pack4(reinterpret_cast<const float4*>(src)[i]);
}

// ---------------- sin/cos table [S][32] ----------------
__global__ void k_sincos(float* __restrict__ sin_t, float* __restrict__ cos_t) {
    int idx = blockIdx.x * blockDim.x + threadIdx.x;
    if (idx >= S_ * 32) return;
    int s = idx >> 5, i = idx & 31;
    float ex = (float)(2 * i) / 64.0f;
    float invf = 1.0f / powf(10000.0f, ex);
    float arg = (float)s * invf;
    sin_t[idx] = (float)sin((double)arg);
    cos_t[idx] = (float)cos((double)arg);
}

// ============== R8 GEMM core (known-good) ==============
// BM=256, BN=128, BK=64, 8 waves (4M x 2N), per-wave 64x64, triple-buffered
// 72KB LDS, counted vmcnt(3), XOR granule swizzle (0 conflicts verified).
template<bool OUT_I8>
__device__ __forceinline__ void gemm_core(
    const i8* __restrict__ X, const i8* __restrict__ W, const float* __restrict__ bias,
    void* __restrict__ out, float alpha, int M, int N, int K, i8* lds)
{
    const int nt = K >> 6;
    const int nwg = (M >> 8) * (N >> 7);
    const int q = nwg >> 3;
    const int lin = blockIdx.x;
    const int wg = (lin & 7) * q + (lin >> 3);
    const int nbm = M >> 8;
    const int m0 = (wg % nbm) * 256, n0 = (wg / nbm) * 128;

    const int tid = threadIdx.x, lane = tid & 63, wave = tid >> 6;
    const int wr = wave >> 1, wc = wave & 1, l4 = lane & 15, lh = lane >> 4;

    const int g4 = lh ^ ((l4 >> 1) & 3);
    const int aoff = (wr * 64 + l4) * 64 + g4 * 16;
    const int boff = 16384 + (wc * 64 + l4) * 64 + g4 * 16;

    const int srow = tid >> 2;
    const int sg = (tid & 3) ^ ((tid >> 3) & 3);
    const i8* Asrc = X + (size_t)(m0 + srow) * K + sg * 16;
    const i8* Bsrc = W + (size_t)(n0 + srow) * K + sg * 16;
    const size_t rstep = (size_t)128 * K;
    const int ldst = wave * 1024;

#define BUF3(t_) (lds + ((t_) % 3) * 24576)
#define STAGE3(t_) do { int kb_ = (t_) * 64; i8* lb_ = BUF3(t_);             \
        gload16(Asrc + kb_,         lb_ + ldst);                             \
        gload16(Asrc + rstep + kb_, lb_ + 8192 + ldst);                      \
        gload16(Bsrc + kb_,         lb_ + 16384 + ldst); } while (0)

    int32x4 acc[4][4];
#pragma unroll
    for (int m = 0; m < 4; ++m)
#pragma unroll
        for (int n = 0; n < 4; ++n) acc[m][n] = int32x4{0, 0, 0, 0};

    STAGE3(0);
    STAGE3(1);

    for (int t = 0; t < nt; ++t) {
        const i8* Tb = BUF3(t);
        if (t + 1 < nt) { WAIT_VM3(); } else { WAIT_VM0(); }
        __builtin_amdgcn_s_barrier();
        COMPILER_FENCE();

        if (t + 2 < nt) STAGE3(t + 2);

        int32x4 a0, a1, a2, a3, b0, b1, b2, b3;
        a0 = ld16(Tb + aoff);
        b0 = ld16(Tb + boff);        b1 = ld16(Tb + boff + 1024);
        b2 = ld16(Tb + boff + 2048); b3 = ld16(Tb + boff + 3072);
        a1 = ld16(Tb + aoff + 1024);
        a2 = ld16(Tb + aoff + 2048); a3 = ld16(Tb + aoff + 3072);
        __builtin_amdgcn_s_setprio(1);
        acc[0][0] = MFMA_I8(a0, b0, acc[0][0]);
        acc[0][1] = MFMA_I8(a0, b1, acc[0][1]);
        acc[0][2] = MFMA_I8(a0, b2, acc[0][2]);
        acc[0][3] = MFMA_I8(a0, b3, acc[0][3]);
        acc[1][0] = MFMA_I8(a1, b0, acc[1][0]);
        acc[1][1] = MFMA_I8(a1, b1, acc[1][1]);
        acc[1][2] = MFMA_I8(a1, b2, acc[1][2]);
        acc[1][3] = MFMA_I8(a1, b3, acc[1][3]);
        acc[2][0] = MFMA_I8(a2, b0, acc[2][0]);
        acc[2][1] = MFMA_I8(a2, b1, acc[2][1]);
        acc[2][2] = MFMA_I8(a2, b2, acc[2][2]);
        acc[2][3] = MFMA_I8(a2, b3, acc[2][3]);
        acc[3][0] = MFMA_I8(a3, b0, acc[3][0]);
        acc[3][1] = MFMA_I8(a3, b1, acc[3][1]);
        acc[3][2] = MFMA_I8(a3, b2, acc[3][2]);
        acc[3][3] = MFMA_I8(a3, b3, acc[3][3]);
        __builtin_amdgcn_s_setprio(0);
    }
#undef BUF3
#undef STAGE3

#pragma unroll
    for (int m = 0; m < 4; ++m)
#pragma unroll
        for (int n = 0; n < 4; ++n)
#pragma unroll
            for (int r = 0; r < 4; ++r) {
                int grow = m0 + wr * 64 + m * 16 + lh * 4 + r;
                int gcol = n0 + wc * 64 + n * 16 + l4;
                float y = alpha * (float)acc[m][n][r] + bias[gcol];
                if (OUT_I8) {
                    float v = rintf(y);
                    v = fminf(fmaxf(v, -128.0f), 127.0f);
                    reinterpret_cast<i8*>(out)[(size_t)grow * N + gcol] = (i8)v;
                } else {
                    reinterpret_cast<float*>(out)[(size_t)grow * N + gcol] = y;
                }
            }
}

// fused Q/K/V projection: blockIdx.z selects weight/bias/dst
__global__ __launch_bounds__(512, 4) void k_gemm_qkv(
    const i8* __restrict__ X,
    const i8* __restrict__ w0, const i8* __restrict__ w1, const i8* __restrict__ w2,
    const float* __restrict__ b0, const float* __restrict__ b1, const float* __restrict__ b2,
    i8* __restrict__ o0, i8* __restrict__ o1, i8* __restrict__ o2,
    float alpha, int M, int N, int K)
{
    __shared__ __align__(16) i8 lds[3 * 24576];
    int z = blockIdx.z;
    const i8* W = (z == 0) ? w0 : (z == 1) ? w1 : w2;
    const float* bias = (z == 0) ? b0 : (z == 1) ? b1 : b2;
    i8* out = (z == 0) ? o0 : (z == 1) ? o1 : o2;
    gemm_core<true>(X, W, bias, out, alpha, M, N, K, lds);
}

__global__ __launch_bounds__(512, 4) void k_gemm_out(
    const i8* __restrict__ X, const i8* __restrict__ W, const float* __restrict__ bias,
    float* __restrict__ out, float alpha, int M, int N, int K)
{
    __shared__ __align__(16) i8 lds[3 * 24576];
    gemm_core<false>(X, W, bias, out, alpha, M, N, K, lds);
}

// ---------------- rope, vectorized: (B,S,H,D) -> (B,H,S,D) ----------------
// 16 threads per row, 16B per thread. Rotary pairs (d, d^1) are within the
// thread's own 16B chunk -> no shuffles. Loads fully contiguous (4KB/block);
// stores 256B-contiguous per row. Table reads: 32B/thread, L2-resident.
__global__ void k_rope(const i8* __restrict__ qin, const i8* __restrict__ kin,
                       i8* __restrict__ qout, i8* __restrict__ kout,
                       const float* __restrict__ sin_t, const float* __restrict__ cos_t)
{
    const i8* in = blockIdx.y ? kin : qin;
    i8* outp = blockIdx.y ? kout : qout;
    int t = threadIdx.x;
    int row = blockIdx.x * 16 + (t >> 4);   // (b*S + s)*H + h
    int seg = t & 15;
    int b = row >> 14;                      // / (S*H)
    int s = (row >> 4) & 1023;
    int h = row & 15;
    union { int32x4 v; i8 b8[16]; } u;
    u.v = ld16(in + (size_t)row * D_ + seg * 16);
    if (seg < 4) {                          // d = seg*16 + j < 64
#pragma unroll
        for (int j = 0; j < 16; j += 2) {
            int i = (seg * 16 + j) >> 1;
            float c = cos_t[s * 32 + i], sn = sin_t[s * 32 + i];
            float f1 = (float)u.b8[j], f2 = (float)u.b8[j + 1];
            float r0 = __fadd_rn(__fmul_rn(f1, c), __fmul_rn(-f2, sn));
            float r1 = __fadd_rn(__fmul_rn(f2, c), __fmul_rn(f1, sn));
            u.b8[j]     = (i8)truncf(fminf(fmaxf(r0, -128.0f), 127.0f));
            u.b8[j + 1] = (i8)truncf(fminf(fmaxf(r1, -128.0f), 127.0f));
        }
    }
    *reinterpret_cast<int32x4*>(
        outp + ((size_t)(b * H_ + h) * S_ + s) * D_ + seg * 16) = u.v;
}

// ---------------- V transpose: (B,S,H,D) -> (B,H,D,S) ----------------
__global__ void k_vtrans(const i8* __restrict__ vin, i8* __restrict__ vout) {
    __shared__ int tile[64][17];
    int bh = blockIdx.z;
    int b = bh >> 4, h = bh & 15;
    int s0 = blockIdx.x * 64, d0 = blockIdx.y * 64;
    int t = threadIdx.x;
    {
        int sr = t >> 2, dq = (t & 3) * 16;
        int32x4 v = ld16(vin + ((size_t)(b * S_ + s0 + sr) * H_ + h) * D_ + d0 + dq);
#pragma unroll
        for (int j = 0; j < 4; ++j) tile[sr][dq / 4 + j] = v[j];
    }
    __syncthreads();
    {
        int dr = t >> 2, sq = (t & 3) * 16;
        union { int32x4 v; i8 b[16]; } u;
        const i8* tb = reinterpret_cast<const i8*>(tile);
#pragma unroll
        for (int j = 0; j < 16; ++j) u.b[j] = tb[(sq + j) * 68 + dr];
        *reinterpret_cast<int32x4*>(vout + ((size_t)bh * D_ + d0 + dr) * S_ + s0 + sq) = u.v;
    }
}

// ---------------- fused int8 attention (R8/R14 version) ----------------
// Q,K: (B,H,S,D) post-rope. V: (B,H,D,S). O: (B,S,H,D).
// No-max softmax (|w| <= 51.6 fits fp32 exp). Phase A: lane-local exp-sums.
// Phase B: recompute scores, p = rint(e * 127/sum), PV via int8 MFMA.
struct AttnShared {
    float slx[4][32];
    float r127[32];
    __align__(16) i8 plds[32][80];
};

__device__ __forceinline__ void attn_chunk(int qc, int bh, int tid,
    const i8* __restrict__ Qh, const i8* __restrict__ Kb, const i8* __restrict__ Vb,
    i8* __restrict__ O, AttnShared& sh)
{
    const float C2 = 1.25e-5f * 1.44269504088896f;   // A_QK/16 * log2(e)
    const float APV = 1.0f / 127.0f;
    const int lane = tid & 63, wave = tid >> 6;
    const int l4 = lane & 15, lh = lane >> 4;
    const i8* Qb = Qh + (size_t)(qc * 32) * D_;
    const int nt = (qc * 32 + 31) / 64 + 1;

    int32x4 aq[2][4];
#pragma unroll
    for (int m = 0; m < 2; ++m)
#pragma unroll
        for (int kk = 0; kk < 4; ++kk)
            aq[m][kk] = ld16(Qb + (size_t)(m * 16 + l4) * D_ + kk * 64 + lh * 16);

    float sum_[2][4];
#pragma unroll
    for (int m = 0; m < 2; ++m)
#pragma unroll
        for (int r = 0; r < 4; ++r) sum_[m][r] = 0.0f;

    for (int kt = 0; kt < nt; ++kt) {
        int cb = kt * 64 + wave * 16;
        int32x4 acc0 = int32x4{0,0,0,0}, acc1 = int32x4{0,0,0,0};
#pragma unroll
        for (int kk = 0; kk < 4; ++kk) {
            int32x4 bf = ld16(Kb + (size_t)(cb + l4) * D_ + kk * 64 + lh * 16);
            acc0 = MFMA_I8(aq[0][kk], bf, acc0);
            acc1 = MFMA_I8(aq[1][kk], bf, acc1);
        }
        int gcol = cb + l4;
#pragma unroll
        for (int m = 0; m < 2; ++m) {
            int32x4 accm = m ? acc1 : acc0;
#pragma unroll
            for (int r = 0; r < 4; ++r) {
                int grow = qc * 32 + m * 16 + lh * 4 + r;
                float e = (gcol <= grow) ? exp2f((float)accm[r] * C2) : 0.0f;
                sum_[m][r] += e;
            }
        }
    }

#pragma unroll
    for (int m = 0; m < 2; ++m)
#pragma unroll
        for (int r = 0; r < 4; ++r) {
            float s = sum_[m][r];
            s += __shfl_xor(s, 1);
            s += __shfl_xor(s, 2);
            s += __shfl_xor(s, 4);
            s += __shfl_xor(s, 8);
            if (l4 == 0) sh.slx[wave][m * 16 + lh * 4 + r] = s;
        }
    __syncthreads();
    if (tid < 32)
        sh.r127[tid] = 127.0f /
            (sh.slx[0][tid] + sh.slx[1][tid] + sh.slx[2][tid] + sh.slx[3][tid]);
    __syncthreads();

    int32x4 oacc[2][4];
#pragma unroll
    for (int m = 0; m < 2; ++m)
#pragma unroll
        for (int n = 0; n < 4; ++n) oacc[m][n] = int32x4{0, 0, 0, 0};

    for (int kt = 0; kt < nt; ++kt) {
        int cb = kt * 64 + wave * 16;
        int32x4 acc0 = int32x4{0,0,0,0}, acc1 = int32x4{0,0,0,0};
#pragma unroll
        for (int kk = 0; kk < 4; ++kk) {
            int32x4 bf = ld16(Kb + (size_t)(cb + l4) * D_ + kk * 64 + lh * 16);
            acc0 = MFMA_I8(aq[0][kk], bf, acc0);
            acc1 = MFMA_I8(aq[1][kk], bf, acc1);
        }
        int gcol = cb + l4;
        i8 pv[2][4];
#pragma unroll
        for (int m = 0; m < 2; ++m) {
            int32x4 accm = m ? acc1 : acc0;
#pragma unroll
            for (int r = 0; r < 4; ++r) {
                int rowi = m * 16 + lh * 4 + r;
                int grow = qc * 32 + rowi;
                float e = (gcol <= grow) ? exp2f((float)accm[r] * C2) : 0.0f;
                pv[m][r] = (i8)(int)rintf(e * sh.r127[rowi]);
            }
        }
        __syncthreads();
#pragma unroll
        for (int m = 0; m < 2; ++m)
#pragma unroll
            for (int r = 0; r < 4; ++r)
                sh.plds[m * 16 + lh * 4 + r][wave * 16 + l4] = pv[m][r];
        __syncthreads();
        int32x4 a0 = ld16(&sh.plds[l4][lh * 16]);
        int32x4 a1 = ld16(&sh.plds[16 + l4][lh * 16]);
#pragma unroll
        for (int n = 0; n < 4; ++n) {
            int32x4 bf = ld16(Vb + (size_t)(wave * 64 + n * 16 + l4) * S_ + kt * 64 + lh * 16);
            oacc[0][n] = MFMA_I8(a0, bf, oacc[0][n]);
            oacc[1][n] = MFMA_I8(a1, bf, oacc[1][n]);
        }
    }

    int b = bh >> 4, h = bh & 15;
#pragma unroll
    for (int m = 0; m < 2; ++m)
#pragma unroll
        for (int r = 0; r < 4; ++r) {
            int s = qc * 32 + m * 16 + lh * 4 + r;
#pragma unroll
            for (int n = 0; n < 4; ++n) {
                float o = rintf(APV * (float)oacc[m][n][r]);
                o = fminf(fmaxf(o, -128.0f), 127.0f);
                O[((size_t)(b * S_ + s) * H_ + h) * D_ + wave * 64 + n * 16 + l4] = (i8)o;
            }
        }
}

// Pair chunks (p, 31-p): every block does ~17 k-tiles -> uniform runtime.
__global__ __launch_bounds__(256) void k_attn(const i8* __restrict__ Q, const i8* __restrict__ K,
                                              const i8* __restrict__ V, i8* __restrict__ O)
{
    __shared__ AttnShared sh;
    int bh = blockIdx.x;
    int p = blockIdx.y;
    int tid = threadIdx.x;
    const i8* Qh = Q + (size_t)bh * S_ * D_;
    const i8* Kb = K + (size_t)bh * S_ * D_;
    const i8* Vb = V + (size_t)bh * D_ * S_;
    attn_chunk((S_ / 32 - 1) - p, bh, tid, Qh, Kb, Vb, O, sh);
    attn_chunk(p, bh, tid, Qh, Kb, Vb, O, sh);
}

extern "C" void kernel_launch(void* const* d_in, const int* in_sizes, int n_in,
                              void* d_out, int out_size, void* d_ws, size_t ws_size,
                              hipStream_t stream) {
    const float* hs = (const float*)d_in[0];
    const float* Wq = (const float*)d_in[1];
    const float* Wk = (const float*)d_in[2];
    const float* Wv = (const float*)d_in[3];
    const float* Wo = (const float*)d_in[4];
    const float* bq = (const float*)d_in[5];
    const float* bk = (const float*)d_in[6];
    const float* bv = (const float*)d_in[7];
    const float* bo = (const float*)d_in[8];
    float* out = (float*)d_out;

    size_t off = 0;
    char* wsb = (char*)d_ws;
    auto carve = [&](size_t bytes) { char* p = wsb + off; off += (bytes + 255) & ~(size_t)255; return p; };
    const size_t ME = (size_t)B_ * S_ * E_;   // 8.4 MB
    const size_t EE = (size_t)E_ * E_;        // 16.8 MB
    i8* x8  = (i8*)carve(ME);
    i8* wq8 = (i8*)carve(EE);
    i8* wk8 = (i8*)carve(EE);
    i8* wv8 = (i8*)carve(EE);
    i8* wo8 = (i8*)carve(EE);
    i8* q8  = (i8*)carve(ME);
    i8* k8  = (i8*)carve(ME);
    i8* v8  = (i8*)carve(ME);
    i8* qr  = (i8*)carve(ME);
    i8* kr  = (i8*)carve(ME);
    i8* vt  = (i8*)carve(ME);
    i8* o8  = (i8*)carve(ME);
    float* sin_t = (float*)carve((size_t)S_ * 32 * 4);
    float* cos_t = (float*)carve((size_t)S_ * 32 * 4);

    int n4_me = (int)(ME / 4), n4_ee = (int)(EE / 4);
    k_f32_to_i8<<<(n4_me + 255) / 256, 256, 0, stream>>>(hs, x8, n4_me);
    k_w_to_i8<<<dim3((n4_ee + 255) / 256, 4), 256, 0, stream>>>(
        Wq, Wk, Wv, Wo, wq8, wk8, wv8, wo8, n4_ee);
    k_sincos<<<(S_ * 32 + 255) / 256, 256, 0, stream>>>(sin_t, cos_t);

    const int M = B_ * S_, N = E_, Kd = E_;
    const int nwg = (M / 256) * (N / 128);   // 256 blocks per z
    k_gemm_qkv<<<dim3(nwg, 1, 3), 512, 0, stream>>>(
        x8, wq8, wk8, wv8, bq, bk, bv, q8, k8, v8, 0.00012f, M, N, Kd);

    k_rope<<<dim3((B_ * S_ * H_) / 16, 2), 256, 0, stream>>>(q8, k8, qr, kr, sin_t, cos_t);
    k_vtrans<<<dim3(S_ / 64, D_ / 64, B_ * H_), 256, 0, stream>>>(v8, vt);
    k_attn<<<dim3(B_ * H_, S_ / 64), 256, 0, stream>>>(qr, kr, vt, o8);

    k_gemm_out<<<nwg, 512, 0, stream>>>(o8, wo8, bo, out, 0.01f, M, N, Kd);
}